// Round 1
// baseline (2111.636 us; speedup 1.0000x reference)
//
#include <hip/hip_runtime.h>
#include <hip/hip_bf16.h>

// ---------------- problem constants ----------------
constexpr int kH = 1024, kS = 1024, kB = 2, kKD = 256, kNKV = 4, kG = 4, kNH = 16,
              kHD = 64, kI = 4096, kNOUT = 2560;

// ---------------- workspace layout (float offsets) ----------------
constexpr long OFF_H   = 0;                                  // h: 2048x1024
constexpr long OFF_Q   = OFF_H  + (long)kB * kS * kH;        // Q / attn buffer
constexpr long OFF_K   = OFF_Q  + (long)kB * kS * kH;        // K: 2048x256
constexpr long OFF_V   = OFF_K  + (long)kB * kS * kKD;       // V: 2048x256
constexpr long OFF_O   = OFF_V  + (long)kB * kS * kKD;       // O: 2048x1024
constexpr long OFF_P   = OFF_O  + (long)kB * kS * kH;        // P: 2048x4096
constexpr long OFF_HM  = OFF_P  + (long)kB * kS * kI;        // hmean accum (1024)
constexpr long OFF_QM  = OFF_HM + kH;                        // qmean accum 3*2*1024
constexpr long OFF_RS  = OFF_QM + 3L * kB * kH;              // rowsum B*NH*S
constexpr long OFF_INT = OFF_RS + (long)kB * kNH * kS;       // ints: flag, sel[3], gate[6]

// ---------------- prep: zero accumulators + is_common flag ----------------
__global__ void prep_kernel(const int* __restrict__ ids, float* __restrict__ zr,
                            int zcount, int* __restrict__ flag) {
  __shared__ int ok_s;
  if (threadIdx.x == 0) ok_s = 1;
  __syncthreads();
  int ok = 1;
  for (int i = threadIdx.x; i < kB * kS; i += blockDim.x) ok &= (ids[i] < 1000) ? 1 : 0;
  for (int i = threadIdx.x; i < zcount; i += blockDim.x) zr[i] = 0.f;
  if (!ok) atomicAnd(&ok_s, 0);
  __syncthreads();
  if (threadIdx.x == 0) *flag = ok_s;
}

// ---------------- embedding gather ----------------
__global__ void embed_kernel(const int* __restrict__ ids, const float* __restrict__ emb,
                             const float* __restrict__ semb, const int* __restrict__ flag,
                             float* __restrict__ h) {
  long row = blockIdx.x;
  int id = ids[row];
  int common = *flag;
  int cid = id; if (cid < 0) cid = 0; if (cid > 999) cid = 999;
  const float4* s4 = (const float4*)(common ? (semb + (long)cid * kH) : (emb + (long)id * kH));
  float4* d4 = (float4*)(h + row * kH);
  for (int i = threadIdx.x; i < kH / 4; i += blockDim.x) d4[i] = s4[i];
}

// ---------------- hmean (batch 0, sum over s) ----------------
__global__ void hmean_kernel(const float* __restrict__ h, float* __restrict__ hm) {
  int s0 = blockIdx.x * 32;
  for (int c = threadIdx.x; c < kH; c += blockDim.x) {
    float a = 0.f;
    for (int s = s0; s < s0 + 32; ++s) a += h[(long)s * kH + c];
    atomicAdd(&hm[c], a);
  }
}

// ---------------- layer scores + top-3 selection ----------------
__global__ void scores_kernel(const float* __restrict__ hm, const float* __restrict__ Wls,
                              const float* __restrict__ bls, int* __restrict__ sel) {
  int w = threadIdx.x >> 6, lane = threadIdx.x & 63;
  float acc = 0.f;
  if (w < 3) for (int c = lane; c < kH; c += 64) acc += hm[c] * Wls[w * kH + c];
  #pragma unroll
  for (int off = 32; off; off >>= 1) acc += __shfl_down(acc, off, 64);
  __shared__ float sc[3];
  if (w < 3 && lane == 0) sc[w] = acc * (1.f / kS) + bls[w];
  __syncthreads();
  if (threadIdx.x == 0) {
    int a = 0;
    if (sc[1] > sc[a]) a = 1;
    if (sc[2] > sc[a]) a = 2;
    int b2 = -1; float bb = -3.4e38f;
    for (int i = 0; i < 3; i++) if (i != a && sc[i] > bb) { bb = sc[i]; b2 = i; }
    sel[0] = a; sel[1] = b2; sel[2] = 3 - a - b2;
  }
}

// ---------------- qmean accumulate (both batches) ----------------
__global__ void qmean_kernel(const float* __restrict__ Q, float* __restrict__ qm) {
  int b = blockIdx.y, s0 = blockIdx.x * 32;
  for (int c = threadIdx.x; c < kH; c += blockDim.x) {
    float a = 0.f;
    for (int s = s0; s < s0 + 32; ++s) a += Q[((long)b * kS + s) * kH + c];
    atomicAdd(&qm[b * kH + c], a);
  }
}

// ---------------- per-batch sigmoid gate ----------------
__global__ void gate_kernel(const float* __restrict__ qm, const float* __restrict__ Wbs,
                            const float* __restrict__ bbs, int* __restrict__ g) {
  int b = threadIdx.x >> 6, lane = threadIdx.x & 63;
  float acc = 0.f;
  for (int c = lane; c < kH; c += 64) acc += qm[b * kH + c] * Wbs[c];
  #pragma unroll
  for (int off = 32; off; off >>= 1) acc += __shfl_down(acc, off, 64);
  if (lane == 0) g[b] = ((acc * (1.f / kS) + bbs[0]) > 0.f) ? 1 : 0;
}

// ---------------- rowsum of thresholded softmax ----------------
__device__ __forceinline__ float dot64(const float4* __restrict__ qr, const float* __restrict__ krow) {
  const float4* kp = (const float4*)krow;
  float x0 = 0, x1 = 0, x2 = 0, x3 = 0;
  #pragma unroll
  for (int i = 0; i < 16; i += 4) {
    float4 a0 = qr[i], a1 = qr[i + 1], a2 = qr[i + 2], a3 = qr[i + 3];
    float4 b0 = kp[i], b1 = kp[i + 1], b2 = kp[i + 2], b3 = kp[i + 3];
    x0 += a0.x * b0.x + a0.y * b0.y + a0.z * b0.z + a0.w * b0.w;
    x1 += a1.x * b1.x + a1.y * b1.y + a1.z * b1.z + a1.w * b1.w;
    x2 += a2.x * b2.x + a2.y * b2.y + a2.z * b2.z + a2.w * b2.w;
    x3 += a3.x * b3.x + a3.y * b3.y + a3.z * b3.z + a3.w * b3.w;
  }
  return (x0 + x1) + (x2 + x3);
}

// grid (S/64, NH, B), block 256 (64 rows x 4 q-splits)
__global__ __launch_bounds__(256) void rowsum_kernel(const float* __restrict__ Q,
                                                     const float* __restrict__ Kb,
                                                     const int* __restrict__ gate,
                                                     float* __restrict__ rs) {
  int b = blockIdx.z;
  if (gate && !gate[b]) return;
  int head = blockIdx.y, kv = head >> 2;
  int lane = threadIdx.x & 63, qh = threadIdx.x >> 6;
  int s = blockIdx.x * 64 + lane;
  float4 qr[16];
  const float4* qp = (const float4*)(Q + ((long)b * kS + s) * kH + head * kHD);
  #pragma unroll
  for (int i = 0; i < 16; i++) qr[i] = qp[i];
  const float* kbase = Kb + (long)b * kS * kKD + kv * kHD;
  int q0 = qh * 256, q1 = q0 + 256;
  float m = -1e30f, sum = 0.f;
  for (int q = q0; q < q1; ++q) {
    float x = dot64(qr, kbase + (long)q * kKD) * 0.125f;
    if (x > m) { sum *= __expf(m - x); m = x; }
    sum += __expf(x - m);
  }
  __shared__ float sm[4][64], ss[4][64], st[4][64];
  sm[qh][lane] = m; ss[qh][lane] = sum;
  __syncthreads();
  float M = fmaxf(fmaxf(sm[0][lane], sm[1][lane]), fmaxf(sm[2][lane], sm[3][lane]));
  float Sg = ss[0][lane] * __expf(sm[0][lane] - M) + ss[1][lane] * __expf(sm[1][lane] - M) +
             ss[2][lane] * __expf(sm[2][lane] - M) + ss[3][lane] * __expf(sm[3][lane] - M);
  float thr = 0.01f * Sg;
  float T = 0.f;
  for (int q = q0; q < q1; ++q) {
    float x = dot64(qr, kbase + (long)q * kKD) * 0.125f;
    float e = __expf(x - M);
    T += (e > thr) ? e : 0.f;
  }
  st[qh][lane] = T;
  __syncthreads();
  if (qh == 0)
    rs[((long)b * kNH + head) * kS + s] =
        (st[0][lane] + st[1][lane] + st[2][lane] + st[3][lane]) / Sg;
}

// ---------------- attn = rowsum * V (into Q buffer) ----------------
__global__ void attn_scale_kernel(const float* __restrict__ V, const float* __restrict__ rs,
                                  const int* __restrict__ gate, float* __restrict__ Aout) {
  long row = blockIdx.x;
  int b = (int)(row >> 10);
  if (gate && !gate[b]) return;
  int s = (int)(row & (kS - 1));
  int c = threadIdx.x * 4;
  int head = c >> 6, kv = head >> 2, d = c & 63;
  float r = rs[((long)b * kNH + head) * kS + s];
  float4 v = *(const float4*)(V + row * kKD + kv * kHD + d);
  *(float4*)(Aout + row * kH + c) = make_float4(v.x * r, v.y * r, v.z * r, v.w * r);
}

// ---------------- tiled f32 GEMM: C = A @ W.T ----------------
// A (M,K) row-major, W (N,K) row-major. BM=128, BN=64, BK=16, 256 thr, 8x4/thread.
// li_ptr: runtime layer index -> W += li*wstride. gate: per-batch block early-exit.
template <bool MUL2>
__global__ __launch_bounds__(256) void gemm_kernel(
    const float* __restrict__ A, const float* __restrict__ W0b, const float* __restrict__ W1b,
    float* __restrict__ C, int M, int N, int K,
    const int* __restrict__ li_ptr, long wstride, const int* __restrict__ gate) {
  constexpr int BM = 128, BN = 64, BK = 16;
  constexpr int SA = 132, SW = 68;  // pads chosen: stage-write conflicts <= 2-way
  __shared__ float As[BK][SA];
  __shared__ float Ws0[BK][SW];
  __shared__ float Ws1[MUL2 ? BK : 1][SW];

  const int m0 = blockIdx.y * BM, n0 = blockIdx.x * BN;
  if (gate != nullptr && !gate[m0 >> 10]) return;  // batch-pure blocks (128 | 1024)

  long off = 0;
  if (li_ptr) off = (long)(*li_ptr) * wstride;
  const float* W0 = W0b + off;
  const float* W1 = MUL2 ? (W1b + off) : W0b;

  const int tid = threadIdx.x;
  const int ty = tid >> 4, tx = tid & 15;
  const int wr = tid >> 2, wkq = tid & 3;

  float acc0[8][4] = {};
  float acc1[MUL2 ? 8 : 1][4] = {};

  for (int k0 = 0; k0 < K; k0 += BK) {
    #pragma unroll
    for (int j = 0; j < 2; j++) {
      int idx = tid + j * 256;
      int r = idx >> 2, kq = idx & 3;
      const float4 v = *(const float4*)(A + (long)(m0 + r) * K + (k0 + kq * 4));
      As[kq * 4 + 0][r] = v.x; As[kq * 4 + 1][r] = v.y;
      As[kq * 4 + 2][r] = v.z; As[kq * 4 + 3][r] = v.w;
    }
    {
      const float4 v = *(const float4*)(W0 + (long)(n0 + wr) * K + (k0 + wkq * 4));
      Ws0[wkq * 4 + 0][wr] = v.x; Ws0[wkq * 4 + 1][wr] = v.y;
      Ws0[wkq * 4 + 2][wr] = v.z; Ws0[wkq * 4 + 3][wr] = v.w;
      if constexpr (MUL2) {
        const float4 u = *(const float4*)(W1 + (long)(n0 + wr) * K + (k0 + wkq * 4));
        Ws1[wkq * 4 + 0][wr] = u.x; Ws1[wkq * 4 + 1][wr] = u.y;
        Ws1[wkq * 4 + 2][wr] = u.z; Ws1[wkq * 4 + 3][wr] = u.w;
      }
    }
    __syncthreads();
    #pragma unroll
    for (int kk = 0; kk < BK; kk++) {
      float4 a0 = *(const float4*)&As[kk][ty * 8];
      float4 a1 = *(const float4*)&As[kk][ty * 8 + 4];
      float4 w = *(const float4*)&Ws0[kk][tx * 4];
      float a[8] = {a0.x, a0.y, a0.z, a0.w, a1.x, a1.y, a1.z, a1.w};
      float wv[4] = {w.x, w.y, w.z, w.w};
      #pragma unroll
      for (int i = 0; i < 8; i++)
        #pragma unroll
        for (int j2 = 0; j2 < 4; j2++) acc0[i][j2] += a[i] * wv[j2];
      if constexpr (MUL2) {
        float4 u = *(const float4*)&Ws1[kk][tx * 4];
        float uv[4] = {u.x, u.y, u.z, u.w};
        #pragma unroll
        for (int i = 0; i < 8; i++)
          #pragma unroll
          for (int j2 = 0; j2 < 4; j2++) acc1[i][j2] += a[i] * uv[j2];
      }
    }
    __syncthreads();
  }
  const int rbase = m0 + ty * 8, cbase = n0 + tx * 4;
  #pragma unroll
  for (int i = 0; i < 8; i++) {
    float4 o;
    if constexpr (MUL2)
      o = make_float4(acc0[i][0] * acc1[i][0], acc0[i][1] * acc1[i][1],
                      acc0[i][2] * acc1[i][2], acc0[i][3] * acc1[i][3]);
    else
      o = make_float4(acc0[i][0], acc0[i][1], acc0[i][2], acc0[i][3]);
    *(float4*)(C + (long)(rbase + i) * N + cbase) = o;
  }
}

// ---------------- launch ----------------
extern "C" void kernel_launch(void* const* d_in, const int* in_sizes, int n_in,
                              void* d_out, int out_size, void* d_ws, size_t ws_size,
                              hipStream_t stream) {
  (void)in_sizes; (void)n_in; (void)out_size; (void)ws_size;
  const int*   ids  = (const int*)d_in[0];
  const float* emb  = (const float*)d_in[1];
  const float* semb = (const float*)d_in[2];
  const float* Wq   = (const float*)d_in[3];
  const float* Wk   = (const float*)d_in[4];
  const float* Wv   = (const float*)d_in[5];
  const float* Wo   = (const float*)d_in[6];
  const float* Wg   = (const float*)d_in[7];
  const float* Wu   = (const float*)d_in[8];
  const float* Wd   = (const float*)d_in[9];
  const float* Wls  = (const float*)d_in[10];
  const float* bls  = (const float*)d_in[11];
  const float* Wbs  = (const float*)d_in[12];
  const float* bbs  = (const float*)d_in[13];
  const float* Wout = (const float*)d_in[14];
  float* out = (float*)d_out;
  float* ws  = (float*)d_ws;

  float* h  = ws + OFF_H;
  float* Qb = ws + OFF_Q;
  float* Kb = ws + OFF_K;
  float* Vb = ws + OFF_V;
  float* Ob = ws + OFF_O;
  float* Pb = ws + OFF_P;
  float* hm = ws + OFF_HM;
  float* qm = ws + OFF_QM;
  float* rs = ws + OFF_RS;
  int* ip   = (int*)(ws + OFF_INT);
  int* flag = ip;
  int* sel  = ip + 1;
  int* gate = ip + 4;

  const int M = kB * kS;  // 2048

  prep_kernel<<<1, 256, 0, stream>>>(ids, hm, kH + 3 * kB * kH, flag);
  embed_kernel<<<M, 256, 0, stream>>>(ids, emb, semb, flag, h);
  hmean_kernel<<<32, 256, 0, stream>>>(h, hm);
  scores_kernel<<<1, 192, 0, stream>>>(hm, Wls, bls, sel);

  for (int i = 0; i < 3; i++) {
    const int* li = sel + i;
    int* g_i = gate + 2 * i;
    float* qm_i = qm + (long)i * kB * kH;

    // Q = h @ wq.T
    gemm_kernel<false><<<dim3(kH / 64, M / 128), 256, 0, stream>>>(
        h, Wq, nullptr, Qb, M, kH, kH, li, (long)kH * kH, nullptr);
    qmean_kernel<<<dim3(32, kB), 256, 0, stream>>>(Qb, qm_i);
    gate_kernel<<<1, 128, 0, stream>>>(qm_i, Wbs, bbs, g_i);
    // K, V
    gemm_kernel<false><<<dim3(kKD / 64, M / 128), 256, 0, stream>>>(
        h, Wk, nullptr, Kb, M, kKD, kH, li, (long)kKD * kH, g_i);
    gemm_kernel<false><<<dim3(kKD / 64, M / 128), 256, 0, stream>>>(
        h, Wv, nullptr, Vb, M, kKD, kH, li, (long)kKD * kH, g_i);
    // rowsum of thresholded softmax; attn = rowsum * V (into Qb)
    rowsum_kernel<<<dim3(kS / 64, kNH, kB), 256, 0, stream>>>(Qb, Kb, g_i, rs);
    attn_scale_kernel<<<M, 256, 0, stream>>>(Vb, rs, g_i, Qb);
    // O = attn @ wo.T
    gemm_kernel<false><<<dim3(kH / 64, M / 128), 256, 0, stream>>>(
        Qb, Wo, nullptr, Ob, M, kH, kH, li, (long)kH * kH, g_i);
    // P = (O @ wg.T) * (O @ wu.T)
    gemm_kernel<true><<<dim3(kI / 64, M / 128), 256, 0, stream>>>(
        Ob, Wg, Wu, Pb, M, kI, kH, li, (long)kI * kH, g_i);
    // h = P @ wd.T (only stored for gated batches)
    gemm_kernel<false><<<dim3(kH / 64, M / 128), 256, 0, stream>>>(
        Pb, Wd, nullptr, h, M, kH, kI, li, (long)kH * kI, g_i);
  }
  // out = h @ Wout[:2560].T
  gemm_kernel<false><<<dim3(kNOUT / 64, M / 128), 256, 0, stream>>>(
      h, Wout, nullptr, out, M, kNOUT, kH, nullptr, 0, nullptr);
}

// Round 2
// 999.990 us; speedup vs baseline: 2.1117x; 2.1117x over previous
//
#include <hip/hip_runtime.h>
#include <hip/hip_bf16.h>

// ---------------- problem constants ----------------
constexpr int kH = 1024, kS = 1024, kB = 2, kKD = 256, kNH = 16, kI = 4096, kNOUT = 2560;

typedef __attribute__((ext_vector_type(8))) short short8v;
typedef __attribute__((ext_vector_type(4))) float f32x4;

__device__ __forceinline__ unsigned short f2bf(float f) {
  unsigned u = __float_as_uint(f);
  return (unsigned short)((u + 0x7fffu + ((u >> 16) & 1u)) >> 16);
}
__device__ __forceinline__ float bf2f(unsigned short u) {
  return __uint_as_float(((unsigned)u) << 16);
}

// ---------------- workspace layout (float offsets) ----------------
constexpr long OFF_H    = 0;                         // 2048x1024 f32
constexpr long OFF_HM   = OFF_H + 2097152;           // hmean sums [2][1024]
constexpr long OFF_RS   = OFF_HM + 2048;             // rowsum B*NH*S
constexpr long OFF_INT  = OFF_RS + 32768;            // ints: flag, sel[3], gate[6]
constexpr long OFF_SLAB = OFF_INT + 64;              // 15,204,352 bf16 = 7,602,176 f
constexpr long OFF_HBF  = OFF_SLAB + 7602176;        // 2M bf16
constexpr long OFF_QBF  = OFF_HBF + 1048576;         // 2M bf16 (also attn)
constexpr long OFF_KBF  = OFF_QBF + 1048576;         // 512K bf16
constexpr long OFF_VBF  = OFF_KBF + 262144;          // 512K bf16
constexpr long OFF_OBF  = OFF_VBF + 262144;          // 2M bf16
constexpr long OFF_PBF  = OFF_OBF + 1048576;         // 8M bf16

// slab offsets (in bf16 elements)
constexpr long SB_WQ = 0, SB_WK = 1048576, SB_WV = 1310720, SB_WO = 1572864,
               SB_WG = 2621440, SB_WU = 6815744, SB_WD = 11010048, SB_TOT = 15204352;

// ---------------- prep: is_common flag ----------------
__global__ void prep_kernel(const int* __restrict__ ids, int* __restrict__ flag) {
  __shared__ int ok_s;
  if (threadIdx.x == 0) ok_s = 1;
  __syncthreads();
  int ok = 1;
  for (int i = threadIdx.x; i < kB * kS; i += blockDim.x) ok &= (ids[i] < 1000) ? 1 : 0;
  if (!ok) atomicAnd(&ok_s, 0);
  __syncthreads();
  if (threadIdx.x == 0) *flag = ok_s;
}

// ---------------- embedding gather ----------------
__global__ void embed_kernel(const int* __restrict__ ids, const float* __restrict__ emb,
                             const float* __restrict__ semb, const int* __restrict__ flag,
                             float* __restrict__ h) {
  long row = blockIdx.x;
  int id = ids[row];
  int common = *flag;
  int cid = id; if (cid < 0) cid = 0; if (cid > 999) cid = 999;
  const float4* s4 = (const float4*)(common ? (semb + (long)cid * kH) : (emb + (long)id * kH));
  float4* d4 = (float4*)(h + row * kH);
  for (int i = threadIdx.x; i < kH / 4; i += blockDim.x) d4[i] = s4[i];
}

// ---------------- hmean: per-batch column sums over s (no atomics) ----------------
__global__ void hmean2_kernel(const float* __restrict__ h, float* __restrict__ hm) {
  int b = blockIdx.y;
  int c = blockIdx.x * 256 + threadIdx.x;
  float a = 0.f;
  const float* p = h + ((long)b << 20) + c;
  for (int s = 0; s < kS; ++s) a += p[(long)s * kH];
  hm[b * kH + c] = a;
}

// ---------------- layer scores + top-3 selection (f32, batch 0) ----------------
__global__ void scores_kernel(const float* __restrict__ hm, const float* __restrict__ Wls,
                              const float* __restrict__ bls, int* __restrict__ sel) {
  int w = threadIdx.x >> 6, lane = threadIdx.x & 63;
  float acc = 0.f;
  if (w < 3) for (int c = lane; c < kH; c += 64) acc += hm[c] * Wls[w * kH + c];
  #pragma unroll
  for (int off = 32; off; off >>= 1) acc += __shfl_down(acc, off, 64);
  __shared__ float sc[3];
  if (w < 3 && lane == 0) sc[w] = acc * (1.f / kS) + bls[w];
  __syncthreads();
  if (threadIdx.x == 0) {
    int a = 0;
    if (sc[1] > sc[a]) a = 1;
    if (sc[2] > sc[a]) a = 2;
    int b2 = -1; float bb = -3.4e38f;
    for (int i = 0; i < 3; i++) if (i != a && sc[i] > bb) { bb = sc[i]; b2 = i; }
    sel[0] = a; sel[1] = b2; sel[2] = 3 - a - b2;
  }
}

// ---------------- gate from hmean (f32 exact path): sigmoid((hmean@wq.T)/S . Wbs + bbs) > .5
__global__ void gate2_kernel(const float* __restrict__ hm, const float* __restrict__ Wq,
                             const int* __restrict__ li_p, const float* __restrict__ Wbs,
                             const float* __restrict__ bbs, int* __restrict__ g) {
  int b = blockIdx.x;
  const float* wq = Wq + (long)(*li_p) * kH * kH;
  const float* hv = hm + b * kH;
  float acc = 0.f;
  for (int c = threadIdx.x; c < kH; c += 256) {
    float t = 0.f;
    const float* wr = wq + (long)c * kH;
    for (int i = 0; i < kH; i += 4) {
      float4 hh = *(const float4*)(hv + i);
      float4 ww = *(const float4*)(wr + i);
      t += hh.x * ww.x + hh.y * ww.y + hh.z * ww.z + hh.w * ww.w;
    }
    acc += t * Wbs[c];
  }
  __shared__ float red[4];
  #pragma unroll
  for (int off = 32; off; off >>= 1) acc += __shfl_down(acc, off, 64);
  if ((threadIdx.x & 63) == 0) red[threadIdx.x >> 6] = acc;
  __syncthreads();
  if (threadIdx.x == 0) {
    float x = (red[0] + red[1] + red[2] + red[3]) * (1.f / kS) + bbs[0];
    g[b] = (x > 0.f) ? 1 : 0;
  }
}

// ---------------- weight conversion into per-layer bf16 slab ----------------
__global__ void wconv_kernel(const float* __restrict__ Wq, const float* __restrict__ Wk,
                             const float* __restrict__ Wv, const float* __restrict__ Wo,
                             const float* __restrict__ Wg, const float* __restrict__ Wu,
                             const float* __restrict__ Wd, const int* __restrict__ li_p,
                             const int* __restrict__ gate, unsigned short* __restrict__ slab) {
  long i = ((long)blockIdx.x * 256 + threadIdx.x) * 4;
  if (i >= SB_TOT) return;
  if (i >= SB_WK && !gate[0] && !gate[1]) return;  // only Wq needed when both gates off
  int li = *li_p;
  const float* src; long base, per;
  if      (i < SB_WK) { src = Wq; base = SB_WQ; per = 1048576; }
  else if (i < SB_WV) { src = Wk; base = SB_WK; per = 262144;  }
  else if (i < SB_WO) { src = Wv; base = SB_WV; per = 262144;  }
  else if (i < SB_WG) { src = Wo; base = SB_WO; per = 1048576; }
  else if (i < SB_WU) { src = Wg; base = SB_WG; per = 4194304; }
  else if (i < SB_WD) { src = Wu; base = SB_WU; per = 4194304; }
  else                { src = Wd; base = SB_WD; per = 4194304; }
  float4 v = *(const float4*)(src + (long)li * per + (i - base));
  ushort4 o;
  o.x = f2bf(v.x); o.y = f2bf(v.y); o.z = f2bf(v.z); o.w = f2bf(v.w);
  *(ushort4*)(slab + i) = o;
}

// ---------------- h -> bf16 ----------------
__global__ void hconv_kernel(const float* __restrict__ h, unsigned short* __restrict__ hbf) {
  long i = ((long)blockIdx.x * 256 + threadIdx.x) * 4;
  float4 v = *(const float4*)(h + i);
  ushort4 o;
  o.x = f2bf(v.x); o.y = f2bf(v.y); o.z = f2bf(v.z); o.w = f2bf(v.w);
  *(ushort4*)(hbf + i) = o;
}

// ---------------- bf16 MFMA GEMM: C = A @ B.T  (A: MxK, B: NxK, bf16) ----------------
// BM=128, BN=64, BK=64, 256 thr = 4 waves (2m x 2n), wave tile 64x32 = 4x2 frags 16x16.
// LDS XOR-swizzle byte ^= ((row&7)<<4) on both write and read (conflict-free b128).
template <bool MUL2, bool OUTF32>
__global__ __launch_bounds__(256) void gemm_bf_kernel(
    const unsigned short* __restrict__ A, const unsigned short* __restrict__ B0,
    const unsigned short* __restrict__ B1, void* __restrict__ Cout,
    int M, int N, int K, const int* __restrict__ gate) {
  constexpr int BM = 128, BN = 64, BK = 64;
  __shared__ unsigned short As[BM * BK];
  __shared__ unsigned short Bs0[BN * BK];
  __shared__ unsigned short Bs1[MUL2 ? BN * BK : 8];

  const int m0 = blockIdx.y * BM, n0 = blockIdx.x * BN;
  if (gate != nullptr && !gate[m0 >> 10]) return;  // 128 | 1024: batch-pure blocks

  const int tid = threadIdx.x;
  const int wave = tid >> 6, lane = tid & 63;
  const int lr = lane & 15, lg = lane >> 4;
  const int wm = wave >> 1, wn = wave & 1;

  f32x4 acc[4][2] = {};
  f32x4 acc1[MUL2 ? 4 : 1][2] = {};

  for (int k0 = 0; k0 < K; k0 += BK) {
    #pragma unroll
    for (int j = 0; j < 4; ++j) {
      int c = tid + j * 256;
      int r = c >> 3, c8 = c & 7;
      short8v v = *(const short8v*)(A + (long)(m0 + r) * K + k0 + c8 * 8);
      int byte = (r * 128 + c8 * 16) ^ ((r & 7) << 4);
      *(short8v*)((char*)As + byte) = v;
    }
    #pragma unroll
    for (int j = 0; j < 2; ++j) {
      int c = tid + j * 256;
      int r = c >> 3, c8 = c & 7;
      int byte = (r * 128 + c8 * 16) ^ ((r & 7) << 4);
      *(short8v*)((char*)Bs0 + byte) = *(const short8v*)(B0 + (long)(n0 + r) * K + k0 + c8 * 8);
      if constexpr (MUL2)
        *(short8v*)((char*)Bs1 + byte) = *(const short8v*)(B1 + (long)(n0 + r) * K + k0 + c8 * 8);
    }
    __syncthreads();
    #pragma unroll
    for (int kh = 0; kh < 2; ++kh) {
      const int kb = kh * 64 + lg * 16;  // byte offset of this lane-group's 8 bf16
      short8v a[4], b[2], b1v[2];
      #pragma unroll
      for (int mi = 0; mi < 4; ++mi) {
        int r = wm * 64 + mi * 16 + lr;
        a[mi] = *(const short8v*)((const char*)As + ((r * 128 + kb) ^ ((r & 7) << 4)));
      }
      #pragma unroll
      for (int ni = 0; ni < 2; ++ni) {
        int r = wn * 32 + ni * 16 + lr;
        int byte = (r * 128 + kb) ^ ((r & 7) << 4);
        b[ni] = *(const short8v*)((const char*)Bs0 + byte);
        if constexpr (MUL2) b1v[ni] = *(const short8v*)((const char*)Bs1 + byte);
      }
      #pragma unroll
      for (int mi = 0; mi < 4; ++mi)
        #pragma unroll
        for (int ni = 0; ni < 2; ++ni) {
          acc[mi][ni] = __builtin_amdgcn_mfma_f32_16x16x32_bf16(a[mi], b[ni], acc[mi][ni], 0, 0, 0);
          if constexpr (MUL2)
            acc1[mi][ni] = __builtin_amdgcn_mfma_f32_16x16x32_bf16(a[mi], b1v[ni], acc1[mi][ni], 0, 0, 0);
        }
    }
    __syncthreads();
  }
  #pragma unroll
  for (int mi = 0; mi < 4; ++mi)
    #pragma unroll
    for (int ni = 0; ni < 2; ++ni)
      #pragma unroll
      for (int r = 0; r < 4; ++r) {
        int row = m0 + wm * 64 + mi * 16 + lg * 4 + r;
        int col = n0 + wn * 32 + ni * 16 + lr;
        float v = acc[mi][ni][r];
        if constexpr (MUL2) v *= acc1[mi][ni][r];
        if constexpr (OUTF32) ((float*)Cout)[(long)row * N + col] = v;
        else ((unsigned short*)Cout)[(long)row * N + col] = f2bf(v);
      }
}

// ---------------- rowsum of thresholded softmax via MFMA, 3 passes ----------------
// grid (S/64, NH, B), 256 thr = 4 waves x 16 q-rows. A=Q-frag (regs), B=K-frag (L2).
__global__ __launch_bounds__(256) void rowsum_mfma_kernel(
    const unsigned short* __restrict__ Qbf,  // [2048][1024]
    const unsigned short* __restrict__ Kbf,  // [2048][256]
    const int* __restrict__ gate, float* __restrict__ rs) {
  int b = blockIdx.z;
  if (gate && !gate[b]) return;
  int head = blockIdx.y, kv = head >> 2, qt = blockIdx.x;
  int wv = threadIdx.x >> 6, lane = threadIdx.x & 63;
  int lr = lane & 15, lg = lane >> 4;

  long qrow = ((long)b << 10) + qt * 64 + wv * 16 + lr;
  const unsigned short* qp = Qbf + qrow * kH + head * 64 + lg * 8;
  short8v qlo = *(const short8v*)qp;
  short8v qhi = *(const short8v*)(qp + 32);
  const unsigned short* kb = Kbf + (((long)b << 10) + lr) * kKD + kv * 64 + lg * 8;

  // pass 1: per-row max
  float m0 = -3e38f, m1 = -3e38f, m2 = -3e38f, m3 = -3e38f;
  for (int kt = 0; kt < 64; ++kt) {
    const unsigned short* kp = kb + (long)kt * 16 * kKD;
    short8v klo = *(const short8v*)kp;
    short8v khi = *(const short8v*)(kp + 32);
    f32x4 c = {0.f, 0.f, 0.f, 0.f};
    c = __builtin_amdgcn_mfma_f32_16x16x32_bf16(qlo, klo, c, 0, 0, 0);
    c = __builtin_amdgcn_mfma_f32_16x16x32_bf16(qhi, khi, c, 0, 0, 0);
    m0 = fmaxf(m0, c[0]); m1 = fmaxf(m1, c[1]);
    m2 = fmaxf(m2, c[2]); m3 = fmaxf(m3, c[3]);
  }
  #pragma unroll
  for (int off = 8; off; off >>= 1) {
    m0 = fmaxf(m0, __shfl_xor(m0, off)); m1 = fmaxf(m1, __shfl_xor(m1, off));
    m2 = fmaxf(m2, __shfl_xor(m2, off)); m3 = fmaxf(m3, __shfl_xor(m3, off));
  }
  m0 *= 0.125f; m1 *= 0.125f; m2 *= 0.125f; m3 *= 0.125f;

  // pass 2: denominator
  float s0 = 0, s1 = 0, s2 = 0, s3 = 0;
  for (int kt = 0; kt < 64; ++kt) {
    const unsigned short* kp = kb + (long)kt * 16 * kKD;
    short8v klo = *(const short8v*)kp;
    short8v khi = *(const short8v*)(kp + 32);
    f32x4 c = {0.f, 0.f, 0.f, 0.f};
    c = __builtin_amdgcn_mfma_f32_16x16x32_bf16(qlo, klo, c, 0, 0, 0);
    c = __builtin_amdgcn_mfma_f32_16x16x32_bf16(qhi, khi, c, 0, 0, 0);
    s0 += __expf(c[0] * 0.125f - m0); s1 += __expf(c[1] * 0.125f - m1);
    s2 += __expf(c[2] * 0.125f - m2); s3 += __expf(c[3] * 0.125f - m3);
  }
  #pragma unroll
  for (int off = 8; off; off >>= 1) {
    s0 += __shfl_xor(s0, off); s1 += __shfl_xor(s1, off);
    s2 += __shfl_xor(s2, off); s3 += __shfl_xor(s3, off);
  }
  float th0 = 0.01f * s0, th1 = 0.01f * s1, th2 = 0.01f * s2, th3 = 0.01f * s3;

  // pass 3: thresholded sum
  float t0 = 0, t1 = 0, t2 = 0, t3 = 0;
  for (int kt = 0; kt < 64; ++kt) {
    const unsigned short* kp = kb + (long)kt * 16 * kKD;
    short8v klo = *(const short8v*)kp;
    short8v khi = *(const short8v*)(kp + 32);
    f32x4 c = {0.f, 0.f, 0.f, 0.f};
    c = __builtin_amdgcn_mfma_f32_16x16x32_bf16(qlo, klo, c, 0, 0, 0);
    c = __builtin_amdgcn_mfma_f32_16x16x32_bf16(qhi, khi, c, 0, 0, 0);
    float e0 = __expf(c[0] * 0.125f - m0), e1 = __expf(c[1] * 0.125f - m1);
    float e2 = __expf(c[2] * 0.125f - m2), e3 = __expf(c[3] * 0.125f - m3);
    t0 += (e0 > th0) ? e0 : 0.f; t1 += (e1 > th1) ? e1 : 0.f;
    t2 += (e2 > th2) ? e2 : 0.f; t3 += (e3 > th3) ? e3 : 0.f;
  }
  #pragma unroll
  for (int off = 8; off; off >>= 1) {
    t0 += __shfl_xor(t0, off); t1 += __shfl_xor(t1, off);
    t2 += __shfl_xor(t2, off); t3 += __shfl_xor(t3, off);
  }
  if (lr == 0) {
    long base = ((long)b * kNH + head) * kS + qt * 64 + wv * 16 + lg * 4;
    rs[base + 0] = t0 / s0; rs[base + 1] = t1 / s1;
    rs[base + 2] = t2 / s2; rs[base + 3] = t3 / s3;
  }
}

// ---------------- attn = rowsum * V (bf16 out) ----------------
__global__ void attn_scale_bf_kernel(const unsigned short* __restrict__ V,
                                     const float* __restrict__ rs,
                                     const int* __restrict__ gate,
                                     unsigned short* __restrict__ Aout) {
  long row = blockIdx.x;
  int b = (int)(row >> 10);
  if (gate && !gate[b]) return;
  int s = (int)(row & (kS - 1));
  int c = threadIdx.x * 4;
  int head = c >> 6, kv = head >> 2, d = c & 63;
  float r = rs[((long)b * kNH + head) * kS + s];
  ushort4 v = *(const ushort4*)(V + row * kKD + kv * 64 + d);
  ushort4 o;
  o.x = f2bf(r * bf2f(v.x)); o.y = f2bf(r * bf2f(v.y));
  o.z = f2bf(r * bf2f(v.z)); o.w = f2bf(r * bf2f(v.w));
  *(ushort4*)(Aout + row * kH + c) = o;
}

// ---------------- f32 tiled GEMM (final output only; unchanged from passing round) ----
__global__ __launch_bounds__(256) void gemm_f32_kernel(
    const float* __restrict__ A, const float* __restrict__ W0,
    float* __restrict__ C, int M, int N, int K) {
  constexpr int BM = 128, BN = 64, BK = 16;
  constexpr int SA = 132, SW = 68;
  __shared__ float As[BK][SA];
  __shared__ float Ws0[BK][SW];

  const int m0 = blockIdx.y * BM, n0 = blockIdx.x * BN;
  const int tid = threadIdx.x;
  const int ty = tid >> 4, tx = tid & 15;
  const int wr = tid >> 2, wkq = tid & 3;

  float acc0[8][4] = {};

  for (int k0 = 0; k0 < K; k0 += BK) {
    #pragma unroll
    for (int j = 0; j < 2; j++) {
      int idx = tid + j * 256;
      int r = idx >> 2, kq = idx & 3;
      const float4 v = *(const float4*)(A + (long)(m0 + r) * K + (k0 + kq * 4));
      As[kq * 4 + 0][r] = v.x; As[kq * 4 + 1][r] = v.y;
      As[kq * 4 + 2][r] = v.z; As[kq * 4 + 3][r] = v.w;
    }
    {
      const float4 v = *(const float4*)(W0 + (long)(n0 + wr) * K + (k0 + wkq * 4));
      Ws0[wkq * 4 + 0][wr] = v.x; Ws0[wkq * 4 + 1][wr] = v.y;
      Ws0[wkq * 4 + 2][wr] = v.z; Ws0[wkq * 4 + 3][wr] = v.w;
    }
    __syncthreads();
    #pragma unroll
    for (int kk = 0; kk < BK; kk++) {
      float4 a0 = *(const float4*)&As[kk][ty * 8];
      float4 a1 = *(const float4*)&As[kk][ty * 8 + 4];
      float4 w = *(const float4*)&Ws0[kk][tx * 4];
      float a[8] = {a0.x, a0.y, a0.z, a0.w, a1.x, a1.y, a1.z, a1.w};
      float wv[4] = {w.x, w.y, w.z, w.w};
      #pragma unroll
      for (int i = 0; i < 8; i++)
        #pragma unroll
        for (int j2 = 0; j2 < 4; j2++) acc0[i][j2] += a[i] * wv[j2];
    }
    __syncthreads();
  }
  const int rbase = m0 + ty * 8, cbase = n0 + tx * 4;
  #pragma unroll
  for (int i = 0; i < 8; i++)
    *(float4*)(C + (long)(rbase + i) * N + cbase) =
        make_float4(acc0[i][0], acc0[i][1], acc0[i][2], acc0[i][3]);
}

// ---------------- launch ----------------
extern "C" void kernel_launch(void* const* d_in, const int* in_sizes, int n_in,
                              void* d_out, int out_size, void* d_ws, size_t ws_size,
                              hipStream_t stream) {
  (void)in_sizes; (void)n_in; (void)out_size; (void)ws_size;
  const int*   ids  = (const int*)d_in[0];
  const float* emb  = (const float*)d_in[1];
  const float* semb = (const float*)d_in[2];
  const float* Wq   = (const float*)d_in[3];
  const float* Wk   = (const float*)d_in[4];
  const float* Wv   = (const float*)d_in[5];
  const float* Wo   = (const float*)d_in[6];
  const float* Wg   = (const float*)d_in[7];
  const float* Wu   = (const float*)d_in[8];
  const float* Wd   = (const float*)d_in[9];
  const float* Wls  = (const float*)d_in[10];
  const float* bls  = (const float*)d_in[11];
  const float* Wbs  = (const float*)d_in[12];
  const float* bbs  = (const float*)d_in[13];
  const float* Wout = (const float*)d_in[14];
  float* out = (float*)d_out;
  float* ws  = (float*)d_ws;

  float* h  = ws + OFF_H;
  float* hm = ws + OFF_HM;
  float* rs = ws + OFF_RS;
  int* ip   = (int*)(ws + OFF_INT);
  int* flag = ip;
  int* sel  = ip + 1;
  int* gate = ip + 4;
  unsigned short* slab = (unsigned short*)(ws + OFF_SLAB);
  unsigned short* hbf  = (unsigned short*)(ws + OFF_HBF);
  unsigned short* Qbf  = (unsigned short*)(ws + OFF_QBF);  // also attn
  unsigned short* Kbf  = (unsigned short*)(ws + OFF_KBF);
  unsigned short* Vbf  = (unsigned short*)(ws + OFF_VBF);
  unsigned short* Obf  = (unsigned short*)(ws + OFF_OBF);
  unsigned short* Pbf  = (unsigned short*)(ws + OFF_PBF);

  const int M = kB * kS;  // 2048

  prep_kernel<<<1, 256, 0, stream>>>(ids, flag);
  embed_kernel<<<M, 256, 0, stream>>>(ids, emb, semb, flag, h);
  hmean2_kernel<<<dim3(kH / 256, kB), 256, 0, stream>>>(h, hm);
  scores_kernel<<<1, 192, 0, stream>>>(hm, Wls, bls, sel);

  for (int i = 0; i < 3; i++) {
    const int* li = sel + i;
    int* g_i = gate + 2 * i;

    if (i > 0) hmean2_kernel<<<dim3(kH / 256, kB), 256, 0, stream>>>(h, hm);
    gate2_kernel<<<kB, 256, 0, stream>>>(hm, Wq, li, Wbs, bbs, g_i);
    wconv_kernel<<<(int)(SB_TOT / 1024), 256, 0, stream>>>(Wq, Wk, Wv, Wo, Wg, Wu, Wd,
                                                           li, g_i, slab);
    hconv_kernel<<<2048, 256, 0, stream>>>(h, hbf);

    // Q = h @ wq.T (bf16)
    gemm_bf_kernel<false, false><<<dim3(kH / 64, M / 128), 256, 0, stream>>>(
        hbf, slab + SB_WQ, nullptr, Qbf, M, kH, kH, nullptr);
    // K, V (gated)
    gemm_bf_kernel<false, false><<<dim3(kKD / 64, M / 128), 256, 0, stream>>>(
        hbf, slab + SB_WK, nullptr, Kbf, M, kKD, kH, g_i);
    gemm_bf_kernel<false, false><<<dim3(kKD / 64, M / 128), 256, 0, stream>>>(
        hbf, slab + SB_WV, nullptr, Vbf, M, kKD, kH, g_i);
    // rowsum of thresholded softmax; attn = rowsum * V (into Qbf)
    rowsum_mfma_kernel<<<dim3(kS / 64, kNH, kB), 256, 0, stream>>>(Qbf, Kbf, g_i, rs);
    attn_scale_bf_kernel<<<M, 256, 0, stream>>>(Vbf, rs, g_i, Qbf);
    // O = attn @ wo.T
    gemm_bf_kernel<false, false><<<dim3(kH / 64, M / 128), 256, 0, stream>>>(
        Qbf, slab + SB_WO, nullptr, Obf, M, kH, kH, g_i);
    // P = (O @ wg.T) * (O @ wu.T)
    gemm_bf_kernel<true, false><<<dim3(kI / 64, M / 128), 256, 0, stream>>>(
        Obf, slab + SB_WG, slab + SB_WU, Pbf, M, kI, kH, g_i);
    // h = P @ wd.T (f32 out, gated rows only)
    gemm_bf_kernel<false, true><<<dim3(kH / 64, M / 128), 256, 0, stream>>>(
        Pbf, slab + SB_WD, nullptr, h, M, kH, kI, g_i);
  }
  // out = h @ Wout[:2560].T (f32, exact for ungated rows)
  gemm_f32_kernel<<<dim3(kNOUT / 64, M / 128), 256, 0, stream>>>(h, Wout, out, M, kNOUT, kH);
}

// Round 3
// 447.230 us; speedup vs baseline: 4.7216x; 2.2360x over previous
//
#include <hip/hip_runtime.h>
#include <hip/hip_bf16.h>

// ---------------- problem constants ----------------
constexpr int kH = 1024, kS = 1024, kB = 2, kKD = 256, kNH = 16, kI = 4096, kNOUT = 2560;

typedef __attribute__((ext_vector_type(8))) short short8v;
typedef __attribute__((ext_vector_type(4))) float f32x4;

__device__ __forceinline__ unsigned short f2bf(float f) {
  unsigned u = __float_as_uint(f);
  return (unsigned short)((u + 0x7fffu + ((u >> 16) & 1u)) >> 16);
}
__device__ __forceinline__ float bf2f(unsigned short u) {
  return __uint_as_float(((unsigned)u) << 16);
}

// async global->LDS, 16B per lane. LDS dest must be wave-uniform base (+lane*16 by HW).
__device__ __forceinline__ void gload16(void* lds, const void* g) {
  __builtin_amdgcn_global_load_lds(
      (const __attribute__((address_space(1))) unsigned int*)g,
      (__attribute__((address_space(3))) unsigned int*)lds, 16, 0, 0);
}

// ---------------- workspace layout (float offsets) ----------------
constexpr long OFF_H      = 0;                            // 2048x1024 f32
constexpr long OFF_HM     = OFF_H + 2097152;              // [2][1024]
constexpr long OFF_RS     = OFF_HM + 2048;                // B*NH*S
constexpr long OFF_INT    = OFF_RS + 32768;               // flag, sel[3], gate[6]
constexpr long OFF_GP     = OFF_INT + 64;                 // gate partial [64][1024]
constexpr long OFF_SLAB   = OFF_GP + 65536;               // 15,204,352 bf16
constexpr long OFF_WOUTBF = OFF_SLAB + 7602176;           // 2,621,440 bf16
constexpr long OFF_HBF    = OFF_WOUTBF + 1310720;         // 2M bf16
constexpr long OFF_QBF    = OFF_HBF + 1048576;            // 2M bf16 (also attn)
constexpr long OFF_KBF    = OFF_QBF + 1048576;            // 512K bf16
constexpr long OFF_VBF    = OFF_KBF + 262144;             // 512K bf16
constexpr long OFF_OBF    = OFF_VBF + 262144;             // 2M bf16
constexpr long OFF_PBF    = OFF_OBF + 1048576;            // 8M bf16

// slab offsets (bf16 elements)
constexpr long SB_WQ = 0, SB_WK = 1048576, SB_WV = 1310720, SB_WO = 1572864,
               SB_WG = 2621440, SB_WU = 6815744, SB_WD = 11010048, SB_TOT = 15204352;

// ---------------- prep: is_common flag ----------------
__global__ void prep_kernel(const int* __restrict__ ids, int* __restrict__ flag) {
  __shared__ int ok_s;
  if (threadIdx.x == 0) ok_s = 1;
  __syncthreads();
  int ok = 1;
  for (int i = threadIdx.x; i < kB * kS; i += blockDim.x) ok &= (ids[i] < 1000) ? 1 : 0;
  if (!ok) atomicAnd(&ok_s, 0);
  __syncthreads();
  if (threadIdx.x == 0) *flag = ok_s;
}

// ---------------- embedding gather (writes f32 h AND bf16 hbf) ----------------
__global__ void embed_kernel(const int* __restrict__ ids, const float* __restrict__ emb,
                             const float* __restrict__ semb, const int* __restrict__ flag,
                             float* __restrict__ h, unsigned short* __restrict__ hbf) {
  long row = blockIdx.x;
  int id = ids[row];
  int common = *flag;
  int cid = id; if (cid < 0) cid = 0; if (cid > 999) cid = 999;
  const float4* s4 = (const float4*)(common ? (semb + (long)cid * kH) : (emb + (long)id * kH));
  float4* d4 = (float4*)(h + row * kH);
  int i = threadIdx.x;  // 256 threads, 256 float4 per row
  float4 v = s4[i];
  d4[i] = v;
  ushort4 u;
  u.x = f2bf(v.x); u.y = f2bf(v.y); u.z = f2bf(v.z); u.w = f2bf(v.w);
  *(ushort4*)(hbf + row * kH + i * 4) = u;
}

// ---------------- hmean: per-batch column sums over s ----------------
__global__ void hmean2_kernel(const float* __restrict__ h, float* __restrict__ hm) {
  int b = blockIdx.y;
  int c = blockIdx.x * 256 + threadIdx.x;
  float a = 0.f;
  const float* p = h + ((long)b << 20) + c;
  for (int s = 0; s < kS; ++s) a += p[(long)s * kH];
  hm[b * kH + c] = a;
}

// ---------------- layer scores + top-3 selection (f32, batch 0) ----------------
__global__ void scores_kernel(const float* __restrict__ hm, const float* __restrict__ Wls,
                              const float* __restrict__ bls, int* __restrict__ sel) {
  int w = threadIdx.x >> 6, lane = threadIdx.x & 63;
  float acc = 0.f;
  if (w < 3) for (int c = lane; c < kH; c += 64) acc += hm[c] * Wls[w * kH + c];
  #pragma unroll
  for (int off = 32; off; off >>= 1) acc += __shfl_down(acc, off, 64);
  __shared__ float sc[3];
  if (w < 3 && lane == 0) sc[w] = acc * (1.f / kS) + bls[w];
  __syncthreads();
  if (threadIdx.x == 0) {
    int a = 0;
    if (sc[1] > sc[a]) a = 1;
    if (sc[2] > sc[a]) a = 2;
    int b2 = -1; float bb = -3.4e38f;
    for (int i = 0; i < 3; i++) if (i != a && sc[i] > bb) { bb = sc[i]; b2 = i; }
    sel[0] = a; sel[1] = b2; sel[2] = 3 - a - b2;
  }
}

// ---------------- gate part 1: partial[p][j] = sum_{c in block p} Wbs[c]*wq[c][j] --------
__global__ void gatevec_kernel(const float* __restrict__ Wq, const int* __restrict__ li_p,
                               const float* __restrict__ Wbs, float* __restrict__ partial) {
  int p = blockIdx.x;  // 64 blocks x 16 rows
  const float* wq = Wq + (long)(*li_p) * kH * kH + (long)p * 16 * kH;
  float acc[4] = {0.f, 0.f, 0.f, 0.f};
  for (int c = 0; c < 16; ++c) {
    float wb = Wbs[p * 16 + c];
    #pragma unroll
    for (int u = 0; u < 4; ++u)
      acc[u] += wb * wq[(long)c * kH + threadIdx.x + u * 256];
  }
  #pragma unroll
  for (int u = 0; u < 4; ++u) partial[(long)p * kH + threadIdx.x + u * 256] = acc[u];
}

// ---------------- gate part 2: g[b] = (dot(hm_b, v)/S + bbs > 0) ----------------
__global__ void gatefin_kernel(const float* __restrict__ hm, const float* __restrict__ partial,
                               const float* __restrict__ bbs, int* __restrict__ g) {
  float a0 = 0.f, a1 = 0.f;
  for (int j = threadIdx.x; j < kH; j += 256) {
    float v = 0.f;
    for (int p = 0; p < 64; ++p) v += partial[(long)p * kH + j];
    a0 += v * hm[j];
    a1 += v * hm[kH + j];
  }
  __shared__ float r0[4], r1[4];
  #pragma unroll
  for (int off = 32; off; off >>= 1) { a0 += __shfl_down(a0, off, 64); a1 += __shfl_down(a1, off, 64); }
  if ((threadIdx.x & 63) == 0) { r0[threadIdx.x >> 6] = a0; r1[threadIdx.x >> 6] = a1; }
  __syncthreads();
  if (threadIdx.x == 0) {
    float x0 = (r0[0] + r0[1] + r0[2] + r0[3]) * (1.f / kS) + bbs[0];
    float x1 = (r1[0] + r1[1] + r1[2] + r1[3]) * (1.f / kS) + bbs[0];
    g[0] = (x0 > 0.f) ? 1 : 0;
    g[1] = (x1 > 0.f) ? 1 : 0;
  }
}

// ---------------- weight conversion into per-layer bf16 slab ----------------
__global__ void wconv_kernel(const float* __restrict__ Wq, const float* __restrict__ Wk,
                             const float* __restrict__ Wv, const float* __restrict__ Wo,
                             const float* __restrict__ Wg, const float* __restrict__ Wu,
                             const float* __restrict__ Wd, const int* __restrict__ li_p,
                             const int* __restrict__ gate, unsigned short* __restrict__ slab) {
  if (!gate[0] && !gate[1]) return;  // nothing downstream needs weights
  long i = ((long)blockIdx.x * 256 + threadIdx.x) * 4;
  if (i >= SB_TOT) return;
  int li = *li_p;
  const float* src; long base, per;
  if      (i < SB_WK) { src = Wq; base = SB_WQ; per = 1048576; }
  else if (i < SB_WV) { src = Wk; base = SB_WK; per = 262144;  }
  else if (i < SB_WO) { src = Wv; base = SB_WV; per = 262144;  }
  else if (i < SB_WG) { src = Wo; base = SB_WO; per = 1048576; }
  else if (i < SB_WU) { src = Wg; base = SB_WG; per = 4194304; }
  else if (i < SB_WD) { src = Wu; base = SB_WU; per = 4194304; }
  else                { src = Wd; base = SB_WD; per = 4194304; }
  float4 v = *(const float4*)(src + (long)li * per + (i - base));
  ushort4 o;
  o.x = f2bf(v.x); o.y = f2bf(v.y); o.z = f2bf(v.z); o.w = f2bf(v.w);
  *(ushort4*)(slab + i) = o;
}

// ---------------- Wout -> bf16 (once) ----------------
__global__ void woutconv_kernel(const float* __restrict__ W, unsigned short* __restrict__ o) {
  long i = ((long)blockIdx.x * 256 + threadIdx.x) * 4;
  float4 v = *(const float4*)(W + i);
  ushort4 u;
  u.x = f2bf(v.x); u.y = f2bf(v.y); u.z = f2bf(v.z); u.w = f2bf(v.w);
  *(ushort4*)(o + i) = u;
}

// ---------------- bf16 MFMA GEMM: C = A @ B.T ----------------
// MODE 0: bf16 out. 1: bf16 out = acc0*acc1 (gate*up). 2: dual bf16 out (K,V).
// 3: f32 out C0 + bf16 out C1 (down). 4: f32 out (final).
// BM=128,BN=64,BK=64, 4 waves. Staging via global_load_lds: linear LDS dest,
// source column-chunk XOR pre-swizzle (c8^(r&7)); reads use byte^((r&7)<<4).
template <int MODE>
__global__ __launch_bounds__(256) void gemm_bf_kernel(
    const unsigned short* __restrict__ A, const unsigned short* __restrict__ B0,
    const unsigned short* __restrict__ B1, void* __restrict__ C0, void* __restrict__ C1,
    int M, int N, int K, const int* __restrict__ gate) {
  constexpr bool USE_B1 = (MODE == 1 || MODE == 2);
  constexpr int BM = 128, BN = 64, BK = 64;
  __shared__ unsigned short As[BM * BK];
  __shared__ unsigned short Bs0[BN * BK];
  __shared__ unsigned short Bs1[USE_B1 ? BN * BK : 8];

  const int m0 = blockIdx.y * BM, n0 = blockIdx.x * BN;
  if (gate != nullptr && !gate[m0 >> 10]) return;  // 128 | 1024: batch-pure blocks

  const int tid = threadIdx.x;
  const int wave = tid >> 6, lane = tid & 63;
  const int lr = lane & 15, lg = lane >> 4;
  const int wm = wave >> 1, wn = wave & 1;

  f32x4 acc[4][2] = {};
  f32x4 acc1[USE_B1 ? 4 : 1][2] = {};

  for (int k0 = 0; k0 < K; k0 += BK) {
    #pragma unroll
    for (int j = 0; j < 4; ++j) {
      int c = tid + j * 256;
      int r = c >> 3, c8 = c & 7;
      gload16((char*)As + (wave * 64 + j * 256) * 16,
              A + (long)(m0 + r) * K + k0 + ((c8 ^ (r & 7)) * 8));
    }
    #pragma unroll
    for (int j = 0; j < 2; ++j) {
      int c = tid + j * 256;
      int r = c >> 3, c8 = c & 7;
      long gb = (long)(n0 + r) * K + k0 + ((c8 ^ (r & 7)) * 8);
      gload16((char*)Bs0 + (wave * 64 + j * 256) * 16, B0 + gb);
      if constexpr (USE_B1)
        gload16((char*)Bs1 + (wave * 64 + j * 256) * 16, B1 + gb);
    }
    __syncthreads();
    #pragma unroll
    for (int kh = 0; kh < 2; ++kh) {
      const int kb = kh * 64 + lg * 16;  // byte offset within row
      short8v a[4], b[2], b1v[2];
      #pragma unroll
      for (int mi = 0; mi < 4; ++mi) {
        int r = wm * 64 + mi * 16 + lr;
        a[mi] = *(const short8v*)((const char*)As + ((r * 128 + kb) ^ ((r & 7) << 4)));
      }
      #pragma unroll
      for (int ni = 0; ni < 2; ++ni) {
        int r = wn * 32 + ni * 16 + lr;
        int byte = (r * 128 + kb) ^ ((r & 7) << 4);
        b[ni] = *(const short8v*)((const char*)Bs0 + byte);
        if constexpr (USE_B1) b1v[ni] = *(const short8v*)((const char*)Bs1 + byte);
      }
      #pragma unroll
      for (int mi = 0; mi < 4; ++mi)
        #pragma unroll
        for (int ni = 0; ni < 2; ++ni) {
          acc[mi][ni] = __builtin_amdgcn_mfma_f32_16x16x32_bf16(a[mi], b[ni], acc[mi][ni], 0, 0, 0);
          if constexpr (USE_B1)
            acc1[mi][ni] = __builtin_amdgcn_mfma_f32_16x16x32_bf16(a[mi], b1v[ni], acc1[mi][ni], 0, 0, 0);
        }
    }
    __syncthreads();
  }
  #pragma unroll
  for (int mi = 0; mi < 4; ++mi)
    #pragma unroll
    for (int ni = 0; ni < 2; ++ni)
      #pragma unroll
      for (int r = 0; r < 4; ++r) {
        long idx = (long)(m0 + wm * 64 + mi * 16 + lg * 4 + r) * N + (n0 + wn * 32 + ni * 16 + lr);
        float v = acc[mi][ni][r];
        if constexpr (MODE == 0) ((unsigned short*)C0)[idx] = f2bf(v);
        if constexpr (MODE == 1) ((unsigned short*)C0)[idx] = f2bf(v * acc1[mi][ni][r]);
        if constexpr (MODE == 2) {
          ((unsigned short*)C0)[idx] = f2bf(v);
          ((unsigned short*)C1)[idx] = f2bf(acc1[mi][ni][r]);
        }
        if constexpr (MODE == 3) {
          ((float*)C0)[idx] = v;
          ((unsigned short*)C1)[idx] = f2bf(v);
        }
        if constexpr (MODE == 4) ((float*)C0)[idx] = v;
      }
}

// ---------------- rowsum of thresholded softmax via MFMA, 2 passes ----------------
// grid (S/64, NH, B), 256 thr = 4 waves x 16 q-rows each.
__global__ __launch_bounds__(256) void rowsum_mfma_kernel(
    const unsigned short* __restrict__ Qbf, const unsigned short* __restrict__ Kbf,
    const int* __restrict__ gate, float* __restrict__ rs) {
  int b = blockIdx.z;
  if (gate && !gate[b]) return;
  int head = blockIdx.y, kv = head >> 2, qt = blockIdx.x;
  int wv = threadIdx.x >> 6, lane = threadIdx.x & 63;
  int lr = lane & 15, lg = lane >> 4;

  long qrow = ((long)b << 10) + qt * 64 + wv * 16 + lr;
  const unsigned short* qp = Qbf + qrow * kH + head * 64 + lg * 8;
  short8v qlo = *(const short8v*)qp;
  short8v qhi = *(const short8v*)(qp + 32);
  const unsigned short* kb = Kbf + (((long)b << 10) + lr) * kKD + kv * 64 + lg * 8;

  // pass 1: online max+denominator
  float m[4] = {-3e38f, -3e38f, -3e38f, -3e38f}, s[4] = {0.f, 0.f, 0.f, 0.f};
  for (int kt = 0; kt < 64; ++kt) {
    const unsigned short* kp = kb + (long)kt * 16 * kKD;
    short8v klo = *(const short8v*)kp;
    short8v khi = *(const short8v*)(kp + 32);
    f32x4 c = {0.f, 0.f, 0.f, 0.f};
    c = __builtin_amdgcn_mfma_f32_16x16x32_bf16(qlo, klo, c, 0, 0, 0);
    c = __builtin_amdgcn_mfma_f32_16x16x32_bf16(qhi, khi, c, 0, 0, 0);
    #pragma unroll
    for (int i = 0; i < 4; ++i) {
      float x = c[i] * 0.125f;
      float mn = fmaxf(m[i], x);
      s[i] = s[i] * __expf(m[i] - mn) + __expf(x - mn);
      m[i] = mn;
    }
  }
  #pragma unroll
  for (int off = 1; off < 16; off <<= 1) {
    #pragma unroll
    for (int i = 0; i < 4; ++i) {
      float mo = __shfl_xor(m[i], off);
      float so = __shfl_xor(s[i], off);
      float mn = fmaxf(m[i], mo);
      s[i] = s[i] * __expf(m[i] - mn) + so * __expf(mo - mn);
      m[i] = mn;
    }
  }
  // pass 2: thresholded sum (e > 0.01*S  <=>  aw > 0.01)
  float t[4] = {0.f, 0.f, 0.f, 0.f};
  for (int kt = 0; kt < 64; ++kt) {
    const unsigned short* kp = kb + (long)kt * 16 * kKD;
    short8v klo = *(const short8v*)kp;
    short8v khi = *(const short8v*)(kp + 32);
    f32x4 c = {0.f, 0.f, 0.f, 0.f};
    c = __builtin_amdgcn_mfma_f32_16x16x32_bf16(qlo, klo, c, 0, 0, 0);
    c = __builtin_amdgcn_mfma_f32_16x16x32_bf16(qhi, khi, c, 0, 0, 0);
    #pragma unroll
    for (int i = 0; i < 4; ++i) {
      float e = __expf(c[i] * 0.125f - m[i]);
      t[i] += (e > 0.01f * s[i]) ? e : 0.f;
    }
  }
  #pragma unroll
  for (int off = 1; off < 16; off <<= 1)
    #pragma unroll
    for (int i = 0; i < 4; ++i) t[i] += __shfl_xor(t[i], off);
  if (lr == 0) {
    long base = ((long)b * kNH + head) * kS + qt * 64 + wv * 16 + lg * 4;
    #pragma unroll
    for (int i = 0; i < 4; ++i) rs[base + i] = t[i] / s[i];
  }
}

// ---------------- attn = rowsum * V (bf16 out) ----------------
__global__ void attn_scale_bf_kernel(const unsigned short* __restrict__ V,
                                     const float* __restrict__ rs,
                                     const int* __restrict__ gate,
                                     unsigned short* __restrict__ Aout) {
  long row = blockIdx.x;
  int b = (int)(row >> 10);
  if (gate && !gate[b]) return;
  int s = (int)(row & (kS - 1));
  int c = threadIdx.x * 4;
  int head = c >> 6, kv = head >> 2, d = c & 63;
  float r = rs[((long)b * kNH + head) * kS + s];
  ushort4 v = *(const ushort4*)(V + row * kKD + kv * 64 + d);
  ushort4 o;
  o.x = f2bf(r * bf2f(v.x)); o.y = f2bf(r * bf2f(v.y));
  o.z = f2bf(r * bf2f(v.z)); o.w = f2bf(r * bf2f(v.w));
  *(ushort4*)(Aout + row * kH + c) = o;
}

// ---------------- launch ----------------
extern "C" void kernel_launch(void* const* d_in, const int* in_sizes, int n_in,
                              void* d_out, int out_size, void* d_ws, size_t ws_size,
                              hipStream_t stream) {
  (void)in_sizes; (void)n_in; (void)out_size; (void)ws_size;
  const int*   ids  = (const int*)d_in[0];
  const float* emb  = (const float*)d_in[1];
  const float* semb = (const float*)d_in[2];
  const float* Wq   = (const float*)d_in[3];
  const float* Wk   = (const float*)d_in[4];
  const float* Wv   = (const float*)d_in[5];
  const float* Wo   = (const float*)d_in[6];
  const float* Wg   = (const float*)d_in[7];
  const float* Wu   = (const float*)d_in[8];
  const float* Wd   = (const float*)d_in[9];
  const float* Wls  = (const float*)d_in[10];
  const float* bls  = (const float*)d_in[11];
  const float* Wbs  = (const float*)d_in[12];
  const float* bbs  = (const float*)d_in[13];
  const float* Wout = (const float*)d_in[14];
  float* out = (float*)d_out;
  float* ws  = (float*)d_ws;

  float* h   = ws + OFF_H;
  float* hm  = ws + OFF_HM;
  float* rs  = ws + OFF_RS;
  int* ip    = (int*)(ws + OFF_INT);
  int* flag  = ip;
  int* sel   = ip + 1;
  int* gate  = ip + 4;
  float* gp  = ws + OFF_GP;
  unsigned short* slab   = (unsigned short*)(ws + OFF_SLAB);
  unsigned short* woutbf = (unsigned short*)(ws + OFF_WOUTBF);
  unsigned short* hbf    = (unsigned short*)(ws + OFF_HBF);
  unsigned short* Qbf    = (unsigned short*)(ws + OFF_QBF);  // also attn
  unsigned short* Kbf    = (unsigned short*)(ws + OFF_KBF);
  unsigned short* Vbf    = (unsigned short*)(ws + OFF_VBF);
  unsigned short* Obf    = (unsigned short*)(ws + OFF_OBF);
  unsigned short* Pbf    = (unsigned short*)(ws + OFF_PBF);

  const int M = kB * kS;  // 2048

  prep_kernel<<<1, 256, 0, stream>>>(ids, flag);
  embed_kernel<<<M, 256, 0, stream>>>(ids, emb, semb, flag, h, hbf);
  hmean2_kernel<<<dim3(kH / 256, kB), 256, 0, stream>>>(h, hm);
  scores_kernel<<<1, 192, 0, stream>>>(hm, Wls, bls, sel);
  woutconv_kernel<<<2560, 256, 0, stream>>>(Wout, woutbf);

  for (int i = 0; i < 3; i++) {
    const int* li = sel + i;
    int* g_i = gate + 2 * i;

    if (i > 0) hmean2_kernel<<<dim3(kH / 256, kB), 256, 0, stream>>>(h, hm);
    gatevec_kernel<<<64, 256, 0, stream>>>(Wq, li, Wbs, gp);
    gatefin_kernel<<<1, 256, 0, stream>>>(hm, gp, bbs, g_i);
    wconv_kernel<<<(int)(SB_TOT / 1024), 256, 0, stream>>>(Wq, Wk, Wv, Wo, Wg, Wu, Wd,
                                                           li, g_i, slab);
    // Q = h @ wq.T (gated: only needed for attention of gated batches)
    gemm_bf_kernel<0><<<dim3(kH / 64, M / 128), 256, 0, stream>>>(
        hbf, slab + SB_WQ, nullptr, Qbf, nullptr, M, kH, kH, g_i);
    // K and V in one pass (shared A-staging)
    gemm_bf_kernel<2><<<dim3(kKD / 64, M / 128), 256, 0, stream>>>(
        hbf, slab + SB_WK, slab + SB_WV, Kbf, Vbf, M, kKD, kH, g_i);
    // rowsum of thresholded softmax; attn = rowsum * V (into Qbf)
    rowsum_mfma_kernel<<<dim3(kS / 64, kNH, kB), 256, 0, stream>>>(Qbf, Kbf, g_i, rs);
    attn_scale_bf_kernel<<<M, 256, 0, stream>>>(Vbf, rs, g_i, Qbf);
    // O = attn @ wo.T
    gemm_bf_kernel<0><<<dim3(kH / 64, M / 128), 256, 0, stream>>>(
        Qbf, slab + SB_WO, nullptr, Obf, nullptr, M, kH, kH, g_i);
    // P = (O @ wg.T) * (O @ wu.T)
    gemm_bf_kernel<1><<<dim3(kI / 64, M / 128), 256, 0, stream>>>(
        Obf, slab + SB_WG, slab + SB_WU, Pbf, nullptr, M, kI, kH, g_i);
    // h = P @ wd.T -> f32 h + bf16 hbf (gated rows only)
    gemm_bf_kernel<3><<<dim3(kH / 64, M / 128), 256, 0, stream>>>(
        Pbf, slab + SB_WD, nullptr, h, hbf, M, kH, kI, g_i);
  }
  // out = h @ Wout[:2560].T (bf16 MFMA, f32 out)
  gemm_bf_kernel<4><<<dim3(kNOUT / 64, M / 128), 256, 0, stream>>>(
      hbf, woutbf, nullptr, out, nullptr, M, kNOUT, kH, nullptr);
}